// Round 1
// baseline (496.294 us; speedup 1.0000x reference)
//
#include <hip/hip_runtime.h>

// MultiHeadAttention: B=4, T=2048, D=1024, H=16, HD=64, causal.
// Pipeline: cvt x->bf16; cvt+transpose W; bf16 MFMA QKV GEMM -> qkv[8192][3072];
// flash attention (online softmax) -> attn[8192][1024] bf16; bf16 MFMA out-proj -> fp32 d_out.

typedef unsigned short u16;
typedef unsigned int u32;
typedef __attribute__((ext_vector_type(8))) short short8;   // 8 x bf16 MFMA operand
typedef __attribute__((ext_vector_type(4))) float f32x4;    // MFMA accumulator

#define LOG2E 1.44269504088896340736f
#define MASKV (-1e30f)

__device__ __forceinline__ u16 f2bf(float f) {
  union { float f; u32 u; } x; x.f = f;
  u32 r = x.u + 0x7FFFu + ((x.u >> 16) & 1u);   // round-to-nearest-even
  return (u16)(r >> 16);
}

// ---------------- convert x: fp32 -> bf16, 4 elems/thread ----------------
__global__ void cvt_x_kernel(const float* __restrict__ x, u16* __restrict__ xb) {
  size_t i = ((size_t)blockIdx.x * 256 + threadIdx.x) * 4;
  float4 v = *(const float4*)(x + i);
  uint2 o;
  o.x = (u32)f2bf(v.x) | ((u32)f2bf(v.y) << 16);
  o.y = (u32)f2bf(v.z) | ((u32)f2bf(v.w) << 16);
  *(uint2*)(xb + i) = o;
}

// ------- convert + transpose weight: src[K][N] fp32 -> dst[N][K] bf16 -------
__global__ void cvt_tr_kernel(const float* __restrict__ src, u16* __restrict__ dst,
                              int K, int N) {
  __shared__ float tile[32][33];
  int n0 = blockIdx.x * 32, k0 = blockIdx.y * 32;
  int tx = threadIdx.x & 31, ty = threadIdx.x >> 5;
  #pragma unroll
  for (int r = ty; r < 32; r += 8)
    tile[r][tx] = src[(size_t)(k0 + r) * N + n0 + tx];
  __syncthreads();
  #pragma unroll
  for (int r = ty; r < 32; r += 8)
    dst[(size_t)(n0 + r) * K + k0 + tx] = f2bf(tile[tx][r]);
}

// ---------------- GEMM: C[M][N] = A[M][K] * Bt[N][K]^T + bias ----------------
// 128x128 tile, 4 waves of 64x64, BK=32, 16x16x32 bf16 MFMA.
template<bool BF16OUT>
__global__ __launch_bounds__(256) void gemm_bt(const u16* __restrict__ A,
                                               const u16* __restrict__ Bt,
                                               const float* __restrict__ bias,
                                               void* __restrict__ Cv, int N) {
  constexpr int K = 1024;
  constexpr int LD = 40;   // 80B row stride: 20 dwords -> spread banks on frag reads
  __shared__ alignas(16) u16 As[128 * LD];
  __shared__ alignas(16) u16 Bs[128 * LD];
  const int t = threadIdx.x;
  const int w = t >> 6, lane = t & 63, quad = lane >> 4, l15 = lane & 15;
  const int m0 = blockIdx.y * 128, n0 = blockIdx.x * 128;
  const int wm = (w >> 1) * 64, wn = (w & 1) * 64;
  const int r0 = t >> 2, c0 = t & 3;           // staging: 16B chunk (row, c)
  const u16* Ap = A + (size_t)(m0 + r0) * K + c0 * 8;
  const u16* Bp = Bt + (size_t)(n0 + r0) * K + c0 * 8;
  const int st0 = r0 * LD + c0 * 8;
  const int st1 = (r0 + 64) * LD + c0 * 8;
  f32x4 acc[4][4];
  #pragma unroll
  for (int i = 0; i < 4; i++)
    #pragma unroll
    for (int j = 0; j < 4; j++)
      acc[i][j] = (f32x4){0.f, 0.f, 0.f, 0.f};

  for (int k0 = 0; k0 < K; k0 += 32) {
    int4 a0 = *(const int4*)(Ap + k0);
    int4 a1 = *(const int4*)(Ap + (size_t)64 * K + k0);
    int4 b0 = *(const int4*)(Bp + k0);
    int4 b1 = *(const int4*)(Bp + (size_t)64 * K + k0);
    __syncthreads();                 // prior tile's frag reads done
    *(int4*)(As + st0) = a0;
    *(int4*)(As + st1) = a1;
    *(int4*)(Bs + st0) = b0;
    *(int4*)(Bs + st1) = b1;
    __syncthreads();
    short8 af[4], bf[4];
    #pragma unroll
    for (int i = 0; i < 4; i++)
      af[i] = *(const short8*)(As + (wm + i * 16 + l15) * LD + quad * 8);
    #pragma unroll
    for (int j = 0; j < 4; j++)
      bf[j] = *(const short8*)(Bs + (wn + j * 16 + l15) * LD + quad * 8);
    #pragma unroll
    for (int i = 0; i < 4; i++)
      #pragma unroll
      for (int j = 0; j < 4; j++)
        acc[i][j] = __builtin_amdgcn_mfma_f32_16x16x32_bf16(af[i], bf[j], acc[i][j], 0, 0, 0);
  }
  // epilogue: C row = quad*4+r, col = lane&15 (verified C/D layout)
  #pragma unroll
  for (int j = 0; j < 4; j++) {
    const int col = n0 + wn + j * 16 + l15;
    const float bv = bias[col];
    #pragma unroll
    for (int i = 0; i < 4; i++) {
      const int row = m0 + wm + i * 16 + quad * 4;
      #pragma unroll
      for (int r = 0; r < 4; r++) {
        float v = acc[i][j][r] + bv;
        if (BF16OUT) ((u16*)Cv)[(size_t)(row + r) * N + col] = f2bf(v);
        else         ((float*)Cv)[(size_t)(row + r) * N + col] = v;
      }
    }
  }
}

// ---------------- flash attention, causal ----------------
// Block: 64 queries of one (b,h); 4 waves x 16 queries. K-tiles of 64 keys.
__global__ __launch_bounds__(256) void flash_kernel(const u16* __restrict__ qkv,
                                                    u16* __restrict__ attn) {
  constexpr int T = 2048, N3 = 3072, LDK = 72;  // 144B stride = 36 dw == 4 mod 32 -> 2-way free
  __shared__ alignas(16) u16 Ks[64 * LDK];       // K rows [key][d]
  __shared__ alignas(16) u16 VsT[64 * LDK];      // V transposed [d][key]
  __shared__ alignas(16) u16 Ps[4 * 16 * LDK];   // per-wave P in A-layout rows
  const int t = threadIdx.x;
  const int w = t >> 6, lane = t & 63, quad = lane >> 4, l15 = lane & 15;
  const int bh = blockIdx.y, b = bh >> 4, h = bh & 15;
  const int qt = (int)gridDim.x - 1 - (int)blockIdx.x;  // heavy tiles first
  const int q0 = qt * 64;
  const int qw = q0 + w * 16;
  const u16* base = qkv + (size_t)b * T * N3 + h * 64;

  // Q fragments, held in registers: A[m=l15][k=quad*8+j], 2 d-steps
  const u16* qrow = base + (size_t)(qw + l15) * N3 + quad * 8;
  short8 qf0 = *(const short8*)(qrow);
  short8 qf1 = *(const short8*)(qrow + 32);

  float m_r[4], l_r[4];
  f32x4 o[4];
  #pragma unroll
  for (int r = 0; r < 4; r++) { m_r[r] = MASKV; l_r[r] = 0.f; }
  #pragma unroll
  for (int d = 0; d < 4; d++) o[d] = (f32x4){0.f, 0.f, 0.f, 0.f};

  const int krow = t >> 3, kc = t & 7;           // K staging: (row, 16B chunk)
  const int vk = (t & 7) | ((t >> 6) << 3);      // V staging: lane-order chosen so
  const int vc = (t >> 3) & 7;                   //   LDS scatter writes spread banks
  const u16* kg = base + 1024 + (size_t)krow * N3 + kc * 8;
  const u16* vg = base + 2048 + (size_t)vk * N3 + vc * 8;

  for (int kt = 0; kt <= qt; ++kt) {
    const size_t koff = (size_t)kt * 64 * N3;
    int4 kv0 = *(const int4*)(kg + koff);
    int4 kv1 = *(const int4*)(kg + koff + (size_t)32 * N3);
    int4 vv0 = *(const int4*)(vg + koff);
    int4 vv1 = *(const int4*)(vg + koff + (size_t)32 * N3);
    __syncthreads();
    *(int4*)(Ks + krow * LDK + kc * 8) = kv0;
    *(int4*)(Ks + (krow + 32) * LDK + kc * 8) = kv1;
    union { int4 v; u16 u[8]; } uv0, uv1;
    uv0.v = vv0; uv1.v = vv1;
    #pragma unroll
    for (int j = 0; j < 8; j++) {               // transpose V into LDS
      VsT[(vc * 8 + j) * LDK + vk] = uv0.u[j];
      VsT[(vc * 8 + j) * LDK + vk + 32] = uv1.u[j];
    }
    __syncthreads();

    // S = Q K^T  (B-frag: K[key=l15+nt*16][d=ds*32+quad*8+j], contiguous 16B)
    f32x4 s[4];
    #pragma unroll
    for (int nt = 0; nt < 4; nt++) s[nt] = (f32x4){0.f, 0.f, 0.f, 0.f};
    #pragma unroll
    for (int nt = 0; nt < 4; nt++) {
      short8 kf0 = *(const short8*)(Ks + (nt * 16 + l15) * LDK + quad * 8);
      short8 kf1 = *(const short8*)(Ks + (nt * 16 + l15) * LDK + 32 + quad * 8);
      s[nt] = __builtin_amdgcn_mfma_f32_16x16x32_bf16(qf0, kf0, s[nt], 0, 0, 0);
      s[nt] = __builtin_amdgcn_mfma_f32_16x16x32_bf16(qf1, kf1, s[nt], 0, 0, 0);
    }

    // scale + causal mask + row max (C layout: row=quad*4+r, col=l15)
    const int k0 = kt * 64;
    float rmax[4];
    #pragma unroll
    for (int r = 0; r < 4; r++) {
      const int row = qw + quad * 4 + r;
      float mx = MASKV;
      #pragma unroll
      for (int nt = 0; nt < 4; nt++) {
        const int col = k0 + nt * 16 + l15;
        float v = s[nt][r] * 0.125f;
        v = (col <= row) ? v : MASKV;
        s[nt][r] = v;
        mx = fmaxf(mx, v);
      }
      rmax[r] = mx;
    }
    #pragma unroll
    for (int m = 1; m < 16; m <<= 1)
      #pragma unroll
      for (int r = 0; r < 4; r++)
        rmax[r] = fmaxf(rmax[r], __shfl_xor(rmax[r], m));

    float alpha[4], rsum[4];
    #pragma unroll
    for (int r = 0; r < 4; r++) {
      float mn = fmaxf(m_r[r], rmax[r]);
      alpha[r] = exp2f((m_r[r] - mn) * LOG2E);
      m_r[r] = mn;
      rsum[r] = 0.f;
    }
    // P = exp(s - m): write to per-wave LDS in A-operand row layout
    u16* pw = Ps + w * 16 * LDK;
    #pragma unroll
    for (int nt = 0; nt < 4; nt++)
      #pragma unroll
      for (int r = 0; r < 4; r++) {
        float p = exp2f((s[nt][r] - m_r[r]) * LOG2E);
        rsum[r] += p;
        pw[(quad * 4 + r) * LDK + nt * 16 + l15] = f2bf(p);
      }
    #pragma unroll
    for (int m = 1; m < 16; m <<= 1)
      #pragma unroll
      for (int r = 0; r < 4; r++)
        rsum[r] += __shfl_xor(rsum[r], m);
    #pragma unroll
    for (int r = 0; r < 4; r++) l_r[r] = l_r[r] * alpha[r] + rsum[r];
    #pragma unroll
    for (int d = 0; d < 4; d++)
      #pragma unroll
      for (int r = 0; r < 4; r++)
        o[d][r] *= alpha[r];

    // O += P V  (A-frag from Ps, B-frag from VsT[d=dt*16+l15][k], contiguous)
    #pragma unroll
    for (int ks = 0; ks < 2; ks++) {
      short8 pf = *(const short8*)(pw + l15 * LDK + ks * 32 + quad * 8);
      #pragma unroll
      for (int d = 0; d < 4; d++) {
        short8 vf = *(const short8*)(VsT + (d * 16 + l15) * LDK + ks * 32 + quad * 8);
        o[d] = __builtin_amdgcn_mfma_f32_16x16x32_bf16(pf, vf, o[d], 0, 0, 0);
      }
    }
  }

  // normalize + store bf16 [B*T][D]
  #pragma unroll
  for (int r = 0; r < 4; r++) {
    const float inv = 1.0f / l_r[r];
    const size_t rowoff = (size_t)(b * T + qw + quad * 4 + r) * 1024 + h * 64;
    #pragma unroll
    for (int d = 0; d < 4; d++)
      attn[rowoff + d * 16 + l15] = f2bf(o[d][r] * inv);
  }
}

extern "C" void kernel_launch(void* const* d_in, const int* in_sizes, int n_in,
                              void* d_out, int out_size, void* d_ws, size_t ws_size,
                              hipStream_t stream) {
  (void)in_sizes; (void)n_in; (void)out_size; (void)ws_size;
  const float* x     = (const float*)d_in[0];
  // d_in[1]: causal mask — statically tril, handled in-kernel
  const float* w_qkv = (const float*)d_in[2];
  const float* b_qkv = (const float*)d_in[3];
  const float* w_out = (const float*)d_in[4];
  const float* b_out = (const float*)d_in[5];
  float* out = (float*)d_out;

  char* ws = (char*)d_ws;
  u16* xb    = (u16*)(ws);                 // 8192*1024  bf16 = 16.78 MB
  u16* wqkvT = (u16*)(ws + 16777216);      // 3072*1024  bf16 =  6.29 MB
  u16* woutT = (u16*)(ws + 23068672);      // 1024*1024  bf16 =  2.10 MB
  u16* qkvb  = (u16*)(ws + 25165824);      // 8192*3072  bf16 = 50.33 MB
  u16* attnb = (u16*)(ws + 75497472);      // 8192*1024  bf16 = 16.78 MB

  cvt_x_kernel<<<8192, 256, 0, stream>>>(x, xb);
  cvt_tr_kernel<<<dim3(96, 32), 256, 0, stream>>>(w_qkv, wqkvT, 1024, 3072);
  cvt_tr_kernel<<<dim3(32, 32), 256, 0, stream>>>(w_out, woutT, 1024, 1024);
  gemm_bt<true ><<<dim3(24, 64), 256, 0, stream>>>(xb, wqkvT, b_qkv, qkvb, 3072);
  flash_kernel<<<dim3(32, 64), 256, 0, stream>>>(qkvb, attnb);
  gemm_bt<false><<<dim3(8, 64), 256, 0, stream>>>(attnb, woutT, b_out, out, 1024);
}

// Round 2
// 400.557 us; speedup vs baseline: 1.2390x; 1.2390x over previous
//
#include <hip/hip_runtime.h>

// MultiHeadAttention: B=4, T=2048, D=1024, H=16, HD=64, causal.
// cvt x->bf16; cvt+transpose W; m97-style async GEMM (QKV); flash attention
// (BQ=128, 32q/wave, async K dbuf + reg-prefetch V, XOR-swizzled LDS); async GEMM (proj).

typedef unsigned short u16;
typedef unsigned int u32;
typedef __attribute__((ext_vector_type(8))) short short8;   // 8 x bf16 MFMA operand
typedef __attribute__((ext_vector_type(4))) float f32x4;    // MFMA accumulator

#define LOG2E 1.44269504088896340736f
#define MASKV (-1e30f)

__device__ __forceinline__ u16 f2bf(float f) {
  union { float f; u32 u; } x; x.f = f;
  u32 r = x.u + 0x7FFFu + ((x.u >> 16) & 1u);   // round-to-nearest-even
  return (u16)(r >> 16);
}

// async global->LDS DMA, 16B per lane. HW semantics: data lands at
// wave-uniform LDS base + lane*16 (m104/m108), so we permute the SOURCE
// pointers to realize swizzled LDS layouts.
__device__ __forceinline__ void async16(const u16* g, u16* l) {
  __builtin_amdgcn_global_load_lds((__attribute__((address_space(1))) void*)g,
                                   (__attribute__((address_space(3))) void*)l,
                                   16, 0, 0);
}

// ---------------- convert x: fp32 -> bf16 ----------------
__global__ void cvt_x_kernel(const float* __restrict__ x, u16* __restrict__ xb) {
  size_t i = ((size_t)blockIdx.x * 256 + threadIdx.x) * 4;
  float4 v = *(const float4*)(x + i);
  uint2 o;
  o.x = (u32)f2bf(v.x) | ((u32)f2bf(v.y) << 16);
  o.y = (u32)f2bf(v.z) | ((u32)f2bf(v.w) << 16);
  *(uint2*)(xb + i) = o;
}

// ------- convert + transpose weight: src[K][N] fp32 -> dst[N][K] bf16 -------
__global__ void cvt_tr_kernel(const float* __restrict__ src, u16* __restrict__ dst,
                              int K, int N) {
  __shared__ float tile[32][33];
  int n0 = blockIdx.x * 32, k0 = blockIdx.y * 32;
  int tx = threadIdx.x & 31, ty = threadIdx.x >> 5;
  #pragma unroll
  for (int r = ty; r < 32; r += 8)
    tile[r][tx] = src[(size_t)(k0 + r) * N + n0 + tx];
  __syncthreads();
  #pragma unroll
  for (int r = ty; r < 32; r += 8)
    dst[(size_t)(n0 + r) * K + k0 + tx] = f2bf(tile[tx][r]);
}

// ---------------- GEMM: C[M][N] = A[M][K] * Bt[N][K]^T + bias ----------------
// m97 pattern: 128x128 tile, BK=32, global_load_lds width 16, unpadded LDS
// rows (32 bf16 = 4 x 16B chunks) with 2-bit source swizzle: phys = log ^ (row&3).
template<bool BF16OUT>
__global__ __launch_bounds__(256) void gemm_bt(const u16* __restrict__ A,
                                               const u16* __restrict__ Bt,
                                               const float* __restrict__ bias,
                                               void* __restrict__ Cv, int N) {
  constexpr int K = 1024;
  __shared__ alignas(16) u16 As[128 * 32];
  __shared__ alignas(16) u16 Bs[128 * 32];
  const int t = threadIdx.x;
  const int w = t >> 6, lane = t & 63, quad = lane >> 4, l15 = lane & 15;
  const int m0 = blockIdx.y * 128, n0 = blockIdx.x * 128;
  const int wm = (w >> 1) * 64, wn = (w & 1) * 64;

  size_t gA[2], gB[2];
  int lds_st[2];
  #pragma unroll
  for (int ii = 0; ii < 2; ii++) {
    const int row = w * 32 + ii * 16 + (lane >> 2);
    const int db = (lane & 3) ^ (row & 3);     // source chunk permutation
    gA[ii] = (size_t)(m0 + row) * K + db * 8;
    gB[ii] = (size_t)(n0 + row) * K + db * 8;
    lds_st[ii] = (w * 32 + ii * 16) * 32 + lane * 8;
  }
  const int fsw = (quad ^ (l15 & 3)) << 3;     // frag-read phys chunk offset (u16)

  f32x4 acc[4][4];
  #pragma unroll
  for (int i = 0; i < 4; i++)
    #pragma unroll
    for (int j = 0; j < 4; j++)
      acc[i][j] = (f32x4){0.f, 0.f, 0.f, 0.f};

  for (int k0 = 0; k0 < K; k0 += 32) {
    __syncthreads();                      // prior tile's frag reads done
    async16(A + gA[0] + k0, As + lds_st[0]);
    async16(A + gA[1] + k0, As + lds_st[1]);
    async16(Bt + gB[0] + k0, Bs + lds_st[0]);
    async16(Bt + gB[1] + k0, Bs + lds_st[1]);
    __syncthreads();                      // drains vmcnt -> LDS ready
    short8 af[4], bf[4];
    #pragma unroll
    for (int i = 0; i < 4; i++)
      af[i] = *(const short8*)(As + (wm + i * 16 + l15) * 32 + fsw);
    #pragma unroll
    for (int j = 0; j < 4; j++)
      bf[j] = *(const short8*)(Bs + (wn + j * 16 + l15) * 32 + fsw);
    #pragma unroll
    for (int i = 0; i < 4; i++)
      #pragma unroll
      for (int j = 0; j < 4; j++)
        acc[i][j] = __builtin_amdgcn_mfma_f32_16x16x32_bf16(af[i], bf[j], acc[i][j], 0, 0, 0);
  }
  // epilogue: C row = quad*4+r, col = lane&15 (verified C/D layout)
  #pragma unroll
  for (int j = 0; j < 4; j++) {
    const int col = n0 + wn + j * 16 + l15;
    const float bv = bias[col];
    #pragma unroll
    for (int i = 0; i < 4; i++) {
      const int row = m0 + wm + i * 16 + quad * 4;
      #pragma unroll
      for (int r = 0; r < 4; r++) {
        float v = acc[i][j][r] + bv;
        if (BF16OUT) ((u16*)Cv)[(size_t)(row + r) * N + col] = f2bf(v);
        else         ((float*)Cv)[(size_t)(row + r) * N + col] = v;
      }
    }
  }
}

// ---------------- flash attention, causal ----------------
// Block: 128 queries of one (b,h); 4 waves x 32 queries. K-tiles of 64 keys.
// LDS tiles are 64-col u16, XOR-swizzled at 16B granularity:
//   phys_chunk(row, colchunk) = (colchunk ^ ((row>>3)&7) ^ (row&7)) & 7
// K: async-DMA double-buffered (source-permuted). V: reg prefetch + conflict-free
// transpose scatter into the other buffer. One barrier per iteration.
__global__ __launch_bounds__(256) void flash_kernel(const u16* __restrict__ qkv,
                                                    u16* __restrict__ attn) {
  constexpr int T = 2048, N3 = 3072;
  __shared__ alignas(16) u16 Ks[2][64 * 64];
  __shared__ alignas(16) u16 VsT[2][64 * 64];
  __shared__ alignas(16) u16 Ps[4][32 * 64];
  const int t = threadIdx.x;
  const int w = t >> 6, lane = t & 63, quad = lane >> 4, l15 = lane & 15;
  const int bh = blockIdx.x, b = bh >> 4, h = bh & 15;   // grid.x=bh: same-bh blocks share XCD L2
  const int qt = (int)gridDim.y - 1 - (int)blockIdx.y;   // heavy q-tiles dispatch first
  const int q0 = qt * 128;
  const int qw = q0 + w * 32;
  const int ktmax = q0 / 64 + 1;
  const u16* base = qkv + (size_t)b * T * N3 + h * 64;
  const u16* Kg = base + 1024;
  const u16* Vg = base + 2048;

  // Q fragments in registers: A[m=l15][k=quad*8+j], 2 m-tiles x 2 d-chunks
  short8 qf[2][2];
  #pragma unroll
  for (int mi = 0; mi < 2; mi++)
    #pragma unroll
    for (int kc = 0; kc < 2; kc++)
      qf[mi][kc] = *(const short8*)(base + (size_t)(qw + mi * 16 + l15) * N3 + kc * 32 + quad * 8);

  // K async staging: wave w, 2 instrs, 8 keys x 128B each; source chunk permuted
  size_t gK[2];
  int ldsK[2];
  #pragma unroll
  for (int ii = 0; ii < 2; ii++) {
    const int key0 = w * 16 + ii * 8;
    const int key = key0 + (lane >> 3);
    const int db = ((lane & 7) ^ (key0 >> 3) ^ (lane >> 3)) & 7;
    gK[ii] = (size_t)key * N3 + db * 8;
    ldsK[ii] = key0 * 64 + lane * 8;
  }
  // V staging: lane loads V[vkey][vchunk*8..+7]; 8 consecutive lanes cover one 128B row
  const int vkey = w * 8 + (lane >> 3);
  const int vchunk = lane & 7;
  const size_t gV = (size_t)vkey * N3 + vchunk * 8;

  int4 vpref[2];
  // preload tile 0
  async16(Kg + gK[0], &Ks[0][ldsK[0]]);
  async16(Kg + gK[1], &Ks[0][ldsK[1]]);
  vpref[0] = *(const int4*)(Vg + gV);
  vpref[1] = *(const int4*)(Vg + gV + (size_t)32 * N3);
  {
    union { int4 v; u16 u[8]; } uv;
    #pragma unroll
    for (int rd = 0; rd < 2; rd++) {
      uv.v = vpref[rd];
      const int kb = w + 4 * rd, ko = lane >> 3;
      #pragma unroll
      for (int j = 0; j < 8; j++)
        VsT[0][(vchunk * 8 + j) * 64 + (((kb ^ vchunk ^ j) & 7) << 3) + ko] = uv.u[j];
    }
  }

  float m_r[2][4], l_r[2][4];
  f32x4 o[2][4];
  #pragma unroll
  for (int mi = 0; mi < 2; mi++)
    #pragma unroll
    for (int r = 0; r < 4; r++) { m_r[mi][r] = MASKV; l_r[mi][r] = 0.f; }
  #pragma unroll
  for (int mi = 0; mi < 2; mi++)
    #pragma unroll
    for (int dt = 0; dt < 4; dt++) o[mi][dt] = (f32x4){0.f, 0.f, 0.f, 0.f};

  int cur = 0;
  for (int kt = 0; kt <= ktmax; ++kt) {
    __syncthreads();   // K-async(kt) drained; scatters + prior reads visible
    const bool live = (kt * 64 <= qw + 31);  // wave-uniform
    const u16* Kc = Ks[cur];
    const u16* Vc = VsT[cur];
    short8 kf[4][2];
    if (live) {
      #pragma unroll
      for (int nt = 0; nt < 4; nt++) {
        const int kx = (nt * 2 + (l15 >> 3)) ^ (l15 & 7);
        #pragma unroll
        for (int ks = 0; ks < 2; ks++)
          kf[nt][ks] = *(const short8*)(Kc + (nt * 16 + l15) * 64 +
                                        ((((ks * 4 + quad) ^ kx) & 7) << 3));
      }
    }
    if (kt < ktmax) {   // prefetch tile kt+1 (issued after barrier, drains at next)
      const size_t koff = (size_t)(kt + 1) * 64 * N3;
      async16(Kg + koff + gK[0], &Ks[cur ^ 1][ldsK[0]]);
      async16(Kg + koff + gK[1], &Ks[cur ^ 1][ldsK[1]]);
      vpref[0] = *(const int4*)(Vg + koff + gV);
      vpref[1] = *(const int4*)(Vg + koff + gV + (size_t)32 * N3);
    }
    if (live) {
      u16* pw = Ps[w];
      #pragma unroll
      for (int mi = 0; mi < 2; mi++) {
        f32x4 s[4];
        #pragma unroll
        for (int nt = 0; nt < 4; nt++) s[nt] = (f32x4){0.f, 0.f, 0.f, 0.f};
        #pragma unroll
        for (int nt = 0; nt < 4; nt++)
          #pragma unroll
          for (int kc = 0; kc < 2; kc++)
            s[nt] = __builtin_amdgcn_mfma_f32_16x16x32_bf16(qf[mi][kc], kf[nt][kc], s[nt], 0, 0, 0);

        // scale + causal mask + row max (C layout: row=quad*4+r, col=l15)
        float rmax[4], alpha[4], rsum[4];
        const int rowb = qw + mi * 16 + quad * 4;
        #pragma unroll
        for (int r = 0; r < 4; r++) {
          float mx = MASKV;
          #pragma unroll
          for (int nt = 0; nt < 4; nt++) {
            const int col = kt * 64 + nt * 16 + l15;
            float v = s[nt][r] * 0.125f;
            v = (col <= rowb + r) ? v : MASKV;
            s[nt][r] = v;
            mx = fmaxf(mx, v);
          }
          rmax[r] = mx;
        }
        #pragma unroll
        for (int m = 1; m < 16; m <<= 1)
          #pragma unroll
          for (int r = 0; r < 4; r++)
            rmax[r] = fmaxf(rmax[r], __shfl_xor(rmax[r], m));
        #pragma unroll
        for (int r = 0; r < 4; r++) {
          const float mn = fmaxf(m_r[mi][r], rmax[r]);
          alpha[r] = __builtin_amdgcn_exp2f((m_r[mi][r] - mn) * LOG2E);
          m_r[mi][r] = mn;
          rsum[r] = 0.f;
        }
        // P = exp(s-m) -> per-wave LDS (swizzled A-layout); scalar b16 writes, <=2-way
        #pragma unroll
        for (int nt = 0; nt < 4; nt++) {
          const int pcs = nt * 2 + (l15 >> 3);
          #pragma unroll
          for (int r = 0; r < 4; r++) {
            float p = __builtin_amdgcn_exp2f((s[nt][r] - m_r[mi][r]) * LOG2E);
            rsum[r] += p;
            const int rl = mi * 16 + quad * 4 + r;
            pw[rl * 64 + (((pcs ^ (rl >> 3) ^ (rl & 7)) & 7) << 3) + (l15 & 7)] = f2bf(p);
          }
        }
        #pragma unroll
        for (int m = 1; m < 16; m <<= 1)
          #pragma unroll
          for (int r = 0; r < 4; r++)
            rsum[r] += __shfl_xor(rsum[r], m);
        #pragma unroll
        for (int r = 0; r < 4; r++) l_r[mi][r] = l_r[mi][r] * alpha[r] + rsum[r];
        #pragma unroll
        for (int dt = 0; dt < 4; dt++)
          #pragma unroll
          for (int r = 0; r < 4; r++)
            o[mi][dt][r] *= alpha[r];
      }
      // O += P V
      const int p0 = (l15 >> 3) ^ (l15 & 7);
      const int p1 = (2 + (l15 >> 3)) ^ (l15 & 7);
      #pragma unroll
      for (int ks = 0; ks < 2; ks++) {
        const int cb = ks * 4 + quad;
        short8 pf0 = *(const short8*)(pw + l15 * 64 + (((cb ^ p0) & 7) << 3));
        short8 pf1 = *(const short8*)(pw + (16 + l15) * 64 + (((cb ^ p1) & 7) << 3));
        #pragma unroll
        for (int dt = 0; dt < 4; dt++) {
          const int d = dt * 16 + l15;
          const int vx = (dt * 2 + (l15 >> 3)) ^ (l15 & 7);
          short8 vf = *(const short8*)(Vc + d * 64 + (((cb ^ vx) & 7) << 3));
          o[0][dt] = __builtin_amdgcn_mfma_f32_16x16x32_bf16(pf0, vf, o[0][dt], 0, 0, 0);
          o[1][dt] = __builtin_amdgcn_mfma_f32_16x16x32_bf16(pf1, vf, o[1][dt], 0, 0, 0);
        }
      }
    }
    if (kt < ktmax) {  // transpose-scatter V(kt+1) into the other buffer (conflict-free)
      u16* Vn = (u16*)VsT[cur ^ 1];
      union { int4 v; u16 u[8]; } uv;
      #pragma unroll
      for (int rd = 0; rd < 2; rd++) {
        uv.v = vpref[rd];
        const int kb = w + 4 * rd, ko = lane >> 3;
        #pragma unroll
        for (int j = 0; j < 8; j++)
          Vn[(vchunk * 8 + j) * 64 + (((kb ^ vchunk ^ j) & 7) << 3) + ko] = uv.u[j];
      }
    }
    cur ^= 1;
  }

  // normalize + store bf16 [B*T][D]
  #pragma unroll
  for (int mi = 0; mi < 2; mi++)
    #pragma unroll
    for (int r = 0; r < 4; r++) {
      const float inv = 1.0f / l_r[mi][r];
      const int row = qw + mi * 16 + quad * 4 + r;
      const size_t off = (size_t)(b * T + row) * 1024 + h * 64;
      #pragma unroll
      for (int dt = 0; dt < 4; dt++)
        attn[off + dt * 16 + l15] = f2bf(o[mi][dt][r] * inv);
    }
}

extern "C" void kernel_launch(void* const* d_in, const int* in_sizes, int n_in,
                              void* d_out, int out_size, void* d_ws, size_t ws_size,
                              hipStream_t stream) {
  (void)in_sizes; (void)n_in; (void)out_size; (void)ws_size;
  const float* x     = (const float*)d_in[0];
  // d_in[1]: causal mask — statically tril, handled in-kernel
  const float* w_qkv = (const float*)d_in[2];
  const float* b_qkv = (const float*)d_in[3];
  const float* w_out = (const float*)d_in[4];
  const float* b_out = (const float*)d_in[5];
  float* out = (float*)d_out;

  char* ws = (char*)d_ws;
  u16* xb    = (u16*)(ws);                 // 8192*1024  bf16 = 16.78 MB
  u16* wqkvT = (u16*)(ws + 16777216);      // 3072*1024  bf16 =  6.29 MB
  u16* woutT = (u16*)(ws + 23068672);      // 1024*1024  bf16 =  2.10 MB
  u16* qkvb  = (u16*)(ws + 25165824);      // 8192*3072  bf16 = 50.33 MB
  u16* attnb = (u16*)(ws + 75497472);      // 8192*1024  bf16 = 16.78 MB

  cvt_x_kernel<<<8192, 256, 0, stream>>>(x, xb);
  cvt_tr_kernel<<<dim3(96, 32), 256, 0, stream>>>(w_qkv, wqkvT, 1024, 3072);
  cvt_tr_kernel<<<dim3(32, 32), 256, 0, stream>>>(w_out, woutT, 1024, 1024);
  gemm_bt<true ><<<dim3(24, 64), 256, 0, stream>>>(xb, wqkvT, b_qkv, qkvb, 3072);
  flash_kernel<<<dim3(64, 16), 256, 0, stream>>>(qkvb, attnb);
  gemm_bt<false><<<dim3(8, 64), 256, 0, stream>>>(attnb, woutT, b_out, out, 1024);
}

// Round 3
// 329.010 us; speedup vs baseline: 1.5084x; 1.2175x over previous
//
#include <hip/hip_runtime.h>

// MultiHeadAttention: B=4, T=2048, D=1024, H=16, HD=64, causal.
// cvt x->bf16; cvt+transpose W; m97-style async GEMM (QKV); flash attention
// (pair-balanced q-tiles, no-max softmax, MFMA row-sum, async K dbuf); GEMM (proj).

typedef unsigned short u16;
typedef unsigned int u32;
typedef __attribute__((ext_vector_type(8))) short short8;   // 8 x bf16 MFMA operand
typedef __attribute__((ext_vector_type(4))) float f32x4;    // MFMA accumulator

#define MASKV (-1e30f)
#define SCLOG 0.1803368801111444f   // log2(e) / 8  (folds softmax scale into exp2 arg)

__device__ __forceinline__ u16 f2bf(float f) {
  union { float f; u32 u; } x; x.f = f;
  u32 r = x.u + 0x7FFFu + ((x.u >> 16) & 1u);   // round-to-nearest-even
  return (u16)(r >> 16);
}

// async global->LDS DMA, 16B per lane; dest = wave-uniform base + lane*16.
__device__ __forceinline__ void async16(const u16* g, u16* l) {
  __builtin_amdgcn_global_load_lds((__attribute__((address_space(1))) void*)g,
                                   (__attribute__((address_space(3))) void*)l,
                                   16, 0, 0);
}

// ---------------- convert x: fp32 -> bf16 ----------------
__global__ void cvt_x_kernel(const float* __restrict__ x, u16* __restrict__ xb) {
  size_t i = ((size_t)blockIdx.x * 256 + threadIdx.x) * 4;
  float4 v = *(const float4*)(x + i);
  uint2 o;
  o.x = (u32)f2bf(v.x) | ((u32)f2bf(v.y) << 16);
  o.y = (u32)f2bf(v.z) | ((u32)f2bf(v.w) << 16);
  *(uint2*)(xb + i) = o;
}

// ------- convert + transpose weight: src[K][N] fp32 -> dst[N][K] bf16 -------
__global__ void cvt_tr_kernel(const float* __restrict__ src, u16* __restrict__ dst,
                              int K, int N) {
  __shared__ float tile[32][33];
  int n0 = blockIdx.x * 32, k0 = blockIdx.y * 32;
  int tx = threadIdx.x & 31, ty = threadIdx.x >> 5;
  #pragma unroll
  for (int r = ty; r < 32; r += 8)
    tile[r][tx] = src[(size_t)(k0 + r) * N + n0 + tx];
  __syncthreads();
  #pragma unroll
  for (int r = ty; r < 32; r += 8)
    dst[(size_t)(n0 + r) * K + k0 + tx] = f2bf(tile[tx][r]);
}

// ---------------- GEMM: C[M][N] = A[M][K] * Bt[N][K]^T + bias ----------------
// m97 pattern: 128x128 tile, BK=32, global_load_lds width 16, unpadded LDS
// rows with 2-bit source swizzle. (unchanged from round 2 - known good)
template<bool BF16OUT>
__global__ __launch_bounds__(256) void gemm_bt(const u16* __restrict__ A,
                                               const u16* __restrict__ Bt,
                                               const float* __restrict__ bias,
                                               void* __restrict__ Cv, int N) {
  constexpr int K = 1024;
  __shared__ alignas(16) u16 As[128 * 32];
  __shared__ alignas(16) u16 Bs[128 * 32];
  const int t = threadIdx.x;
  const int w = t >> 6, lane = t & 63, quad = lane >> 4, l15 = lane & 15;
  const int m0 = blockIdx.y * 128, n0 = blockIdx.x * 128;
  const int wm = (w >> 1) * 64, wn = (w & 1) * 64;

  size_t gA[2], gB[2];
  int lds_st[2];
  #pragma unroll
  for (int ii = 0; ii < 2; ii++) {
    const int row = w * 32 + ii * 16 + (lane >> 2);
    const int db = (lane & 3) ^ (row & 3);
    gA[ii] = (size_t)(m0 + row) * K + db * 8;
    gB[ii] = (size_t)(n0 + row) * K + db * 8;
    lds_st[ii] = (w * 32 + ii * 16) * 32 + lane * 8;
  }
  const int fsw = (quad ^ (l15 & 3)) << 3;

  f32x4 acc[4][4];
  #pragma unroll
  for (int i = 0; i < 4; i++)
    #pragma unroll
    for (int j = 0; j < 4; j++)
      acc[i][j] = (f32x4){0.f, 0.f, 0.f, 0.f};

  for (int k0 = 0; k0 < K; k0 += 32) {
    __syncthreads();
    async16(A + gA[0] + k0, As + lds_st[0]);
    async16(A + gA[1] + k0, As + lds_st[1]);
    async16(Bt + gB[0] + k0, Bs + lds_st[0]);
    async16(Bt + gB[1] + k0, Bs + lds_st[1]);
    __syncthreads();
    short8 af[4], bf[4];
    #pragma unroll
    for (int i = 0; i < 4; i++)
      af[i] = *(const short8*)(As + (wm + i * 16 + l15) * 32 + fsw);
    #pragma unroll
    for (int j = 0; j < 4; j++)
      bf[j] = *(const short8*)(Bs + (wn + j * 16 + l15) * 32 + fsw);
    #pragma unroll
    for (int i = 0; i < 4; i++)
      #pragma unroll
      for (int j = 0; j < 4; j++)
        acc[i][j] = __builtin_amdgcn_mfma_f32_16x16x32_bf16(af[i], bf[j], acc[i][j], 0, 0, 0);
  }
  #pragma unroll
  for (int j = 0; j < 4; j++) {
    const int col = n0 + wn + j * 16 + l15;
    const float bv = bias[col];
    #pragma unroll
    for (int i = 0; i < 4; i++) {
      const int row = m0 + wm + i * 16 + quad * 4;
      #pragma unroll
      for (int r = 0; r < 4; r++) {
        float v = acc[i][j][r] + bv;
        if (BF16OUT) ((u16*)Cv)[(size_t)(row + r) * N + col] = f2bf(v);
        else         ((float*)Cv)[(size_t)(row + r) * N + col] = v;
      }
    }
  }
}

// ---------------- flash attention, causal ----------------
// Block handles TWO q-tiles of 128: {15-p, p} -> uniform 34 iterations/block.
// 4 waves x 32 queries. K async-DMA dbuf; V reg-prefetch + transpose scatter.
// No-max softmax: p = exp2(s * log2(e)/8); l via MFMA ones-column (consistent
// with bf16 P, so truncation bias cancels in o/l). Mask only on diagonal iters.
// P-buffer swizzle: Gray f(row) = (row ^ row>>1)&7 (read- and write-side free).
__global__ __launch_bounds__(256) void flash_kernel(const u16* __restrict__ qkv,
                                                    u16* __restrict__ attn) {
  constexpr int T = 2048, N3 = 3072;
  __shared__ alignas(16) u16 Ks[2][64 * 64];
  __shared__ alignas(16) u16 VsT[2][64 * 64];
  __shared__ alignas(16) u16 Ps[4][32 * 64];
  const int t = threadIdx.x;
  const int w = t >> 6, lane = t & 63, quad = lane >> 4, l15 = lane & 15;
  const int bh = blockIdx.x, b = bh >> 4, h = bh & 15;
  const u16* base = qkv + (size_t)b * T * N3 + h * 64;
  const u16* Kg = base + 1024;
  const u16* Vg = base + 2048;

  // K async staging: wave w, 2 instrs, 8 keys x 128B each; source chunk permuted
  size_t gK[2];
  int ldsK[2];
  #pragma unroll
  for (int ii = 0; ii < 2; ii++) {
    const int key0 = w * 16 + ii * 8;
    const int key = key0 + (lane >> 3);
    const int db = ((lane & 7) ^ (key0 >> 3) ^ (lane >> 3)) & 7;
    gK[ii] = (size_t)key * N3 + db * 8;
    ldsK[ii] = key0 * 64 + lane * 8;
  }
  // V staging: lane loads V[vkey][vchunk*8..+7]
  const int vkey = w * 8 + (lane >> 3);
  const int vchunk = lane & 7;
  const size_t gV = (size_t)vkey * N3 + vchunk * 8;

  short8 onesf;
  #pragma unroll
  for (int j = 0; j < 8; j++) onesf[j] = (short)0x3F80;   // bf16 1.0

  #pragma unroll 1
  for (int half = 0; half < 2; half++) {
    const int qt = half ? (int)blockIdx.y : 15 - (int)blockIdx.y;  // heavy first
    const int q0 = qt * 128;
    const int qw = q0 + w * 32;
    const int ktmax = 2 * qt + 1;

    // Q fragments: A[m=l15][k=quad*8+j], 2 m-tiles x 2 d-chunks
    short8 qf[2][2];
    #pragma unroll
    for (int mi = 0; mi < 2; mi++)
      #pragma unroll
      for (int kc = 0; kc < 2; kc++)
        qf[mi][kc] = *(const short8*)(base + (size_t)(qw + mi * 16 + l15) * N3 + kc * 32 + quad * 8);

    f32x4 o[2][4], lac[2];
    #pragma unroll
    for (int mi = 0; mi < 2; mi++) {
      lac[mi] = (f32x4){0.f, 0.f, 0.f, 0.f};
      #pragma unroll
      for (int dt = 0; dt < 4; dt++) o[mi][dt] = (f32x4){0.f, 0.f, 0.f, 0.f};
    }

    // preload tile 0 (prior half's reads of buf 0 completed before its last barrier)
    async16(Kg + gK[0], &Ks[0][ldsK[0]]);
    async16(Kg + gK[1], &Ks[0][ldsK[1]]);
    {
      int4 vp0 = *(const int4*)(Vg + gV);
      int4 vp1 = *(const int4*)(Vg + gV + (size_t)32 * N3);
      union { int4 v; u16 u[8]; } uv;
      #pragma unroll
      for (int rd = 0; rd < 2; rd++) {
        uv.v = rd ? vp1 : vp0;
        const int kb = w + 4 * rd, ko = lane >> 3;
        #pragma unroll
        for (int j = 0; j < 8; j++)
          VsT[0][(vchunk * 8 + j) * 64 + (((kb ^ vchunk ^ j) & 7) << 3) + ko] = uv.u[j];
      }
    }

    int cur = 0;
    for (int kt = 0; kt <= ktmax; ++kt) {
      __syncthreads();   // drains K-DMA(kt); scatters + prior-iter reads visible
      const bool live = (kt * 64 <= qw + 31);  // wave-uniform
      const u16* Kc = Ks[cur];
      const u16* Vc = VsT[cur];
      short8 kf[4][2];
      if (live) {
        #pragma unroll
        for (int nt = 0; nt < 4; nt++) {
          const int kx = (nt * 2 + (l15 >> 3)) ^ (l15 & 7);
          #pragma unroll
          for (int ks = 0; ks < 2; ks++)
            kf[nt][ks] = *(const short8*)(Kc + (nt * 16 + l15) * 64 +
                                          ((((ks * 4 + quad) ^ kx) & 7) << 3));
        }
      }
      int4 vp0, vp1;
      if (kt < ktmax) {   // prefetch tile kt+1
        const size_t koff = (size_t)(kt + 1) * 64 * N3;
        async16(Kg + koff + gK[0], &Ks[cur ^ 1][ldsK[0]]);
        async16(Kg + koff + gK[1], &Ks[cur ^ 1][ldsK[1]]);
        vp0 = *(const int4*)(Vg + koff + gV);
        vp1 = *(const int4*)(Vg + koff + gV + (size_t)32 * N3);
      }
      if (live) {
        u16* pw = Ps[w];
        const bool needMask = (kt * 64 + 63 > qw);   // wave-uniform: diagonal only
        #pragma unroll
        for (int mi = 0; mi < 2; mi++) {
          f32x4 s[4];
          #pragma unroll
          for (int nt = 0; nt < 4; nt++) s[nt] = (f32x4){0.f, 0.f, 0.f, 0.f};
          #pragma unroll
          for (int nt = 0; nt < 4; nt++)
            #pragma unroll
            for (int kc = 0; kc < 2; kc++)
              s[nt] = __builtin_amdgcn_mfma_f32_16x16x32_bf16(qf[mi][kc], kf[nt][kc], s[nt], 0, 0, 0);
          if (needMask) {
            #pragma unroll
            for (int r = 0; r < 4; r++) {
              const int row = qw + mi * 16 + quad * 4 + r;
              #pragma unroll
              for (int nt = 0; nt < 4; nt++) {
                const int col = kt * 64 + nt * 16 + l15;
                if (col > row) s[nt][r] = MASKV;
              }
            }
          }
          // p = exp2(s*log2e/8), truncate to bf16, store swizzled A-layout
          #pragma unroll
          for (int nt = 0; nt < 4; nt++) {
            const int lc = nt * 2 + (l15 >> 3);
            #pragma unroll
            for (int r = 0; r < 4; r++) {
              const int rl = mi * 16 + quad * 4 + r;
              const float p = __builtin_amdgcn_exp2f(fminf(s[nt][r], 400.f) * SCLOG);
              union { float f; u32 u; } pc; pc.f = p;
              const int fp_ = (rl ^ (rl >> 1)) & 7;
              pw[rl * 64 + (((lc ^ fp_) & 7) << 3) + (l15 & 7)] = (u16)(pc.u >> 16);
            }
          }
        }
        // O += P V ; l += P 1   (Gray swizzle on P reads)
        const int fpr = (l15 ^ (l15 >> 1)) & 7;
        #pragma unroll
        for (int ks = 0; ks < 2; ks++) {
          const int cb = ks * 4 + quad;
          const int ph = (cb ^ fpr) & 7;
          short8 pf0 = *(const short8*)(pw + l15 * 64 + (ph << 3));
          short8 pf1 = *(const short8*)(pw + (16 + l15) * 64 + (ph << 3));
          #pragma unroll
          for (int dt = 0; dt < 4; dt++) {
            const int vx = (dt * 2 + (l15 >> 3)) ^ (l15 & 7);
            short8 vf = *(const short8*)(Vc + (dt * 16 + l15) * 64 + (((cb ^ vx) & 7) << 3));
            o[0][dt] = __builtin_amdgcn_mfma_f32_16x16x32_bf16(pf0, vf, o[0][dt], 0, 0, 0);
            o[1][dt] = __builtin_amdgcn_mfma_f32_16x16x32_bf16(pf1, vf, o[1][dt], 0, 0, 0);
          }
          lac[0] = __builtin_amdgcn_mfma_f32_16x16x32_bf16(pf0, onesf, lac[0], 0, 0, 0);
          lac[1] = __builtin_amdgcn_mfma_f32_16x16x32_bf16(pf1, onesf, lac[1], 0, 0, 0);
        }
      }
      if (kt < ktmax) {  // transpose-scatter V(kt+1) into other buffer
        u16* Vn = (u16*)VsT[cur ^ 1];
        union { int4 v; u16 u[8]; } uv;
        #pragma unroll
        for (int rd = 0; rd < 2; rd++) {
          uv.v = rd ? vp1 : vp0;
          const int kb = w + 4 * rd, ko = lane >> 3;
          #pragma unroll
          for (int j = 0; j < 8; j++)
            Vn[(vchunk * 8 + j) * 64 + (((kb ^ vchunk ^ j) & 7) << 3) + ko] = uv.u[j];
        }
      }
      cur ^= 1;
    }

    // normalize + store bf16 [B*T][D]
    #pragma unroll
    for (int mi = 0; mi < 2; mi++)
      #pragma unroll
      for (int r = 0; r < 4; r++) {
        const float invl = 1.0f / lac[mi][r];
        const int row = qw + mi * 16 + quad * 4 + r;
        const size_t off = (size_t)(b * T + row) * 1024 + h * 64;
        #pragma unroll
        for (int dt = 0; dt < 4; dt++)
          attn[off + dt * 16 + l15] = f2bf(o[mi][dt][r] * invl);
      }
  }
}

extern "C" void kernel_launch(void* const* d_in, const int* in_sizes, int n_in,
                              void* d_out, int out_size, void* d_ws, size_t ws_size,
                              hipStream_t stream) {
  (void)in_sizes; (void)n_in; (void)out_size; (void)ws_size;
  const float* x     = (const float*)d_in[0];
  // d_in[1]: causal mask — statically tril, handled in-kernel
  const float* w_qkv = (const float*)d_in[2];
  const float* b_qkv = (const float*)d_in[3];
  const float* w_out = (const float*)d_in[4];
  const float* b_out = (const float*)d_in[5];
  float* out = (float*)d_out;

  char* ws = (char*)d_ws;
  u16* xb    = (u16*)(ws);                 // 8192*1024  bf16 = 16.78 MB
  u16* wqkvT = (u16*)(ws + 16777216);      // 3072*1024  bf16 =  6.29 MB
  u16* woutT = (u16*)(ws + 23068672);      // 1024*1024  bf16 =  2.10 MB
  u16* qkvb  = (u16*)(ws + 25165824);      // 8192*3072  bf16 = 50.33 MB
  u16* attnb = (u16*)(ws + 75497472);      // 8192*1024  bf16 = 16.78 MB

  cvt_x_kernel<<<8192, 256, 0, stream>>>(x, xb);
  cvt_tr_kernel<<<dim3(96, 32), 256, 0, stream>>>(w_qkv, wqkvT, 1024, 3072);
  cvt_tr_kernel<<<dim3(32, 32), 256, 0, stream>>>(w_out, woutT, 1024, 1024);
  gemm_bt<true ><<<dim3(24, 64), 256, 0, stream>>>(xb, wqkvT, b_qkv, qkvb, 3072);
  flash_kernel<<<dim3(64, 8), 256, 0, stream>>>(qkvb, attnb);
  gemm_bt<false><<<dim3(8, 64), 256, 0, stream>>>(attnb, woutT, b_out, out, 1024);
}